// Round 4
// baseline (438.426 us; speedup 1.0000x reference)
//
#include <hip/hip_runtime.h>

#define HH 1024
#define WW 1024
#define RH 64            // output rows per wave-task
#define CHD (HH / RH)    // 16 row-chunks
#define NSTRIP 9         // col strips
#define SOUT 116         // output cols per strip (wave covers SOUT+12 = 128 cols)
#define SSIM_C1 1e-4f
#define SSIM_C2 9e-4f

__global__ void ssim_ws_init(float* ws) { ws[0] = 0.f; }

__device__ __forceinline__ float shf(int addr, float v) {
    return __int_as_float(__builtin_amdgcn_ds_bpermute(addr, __float_as_int(v)));
}

__global__ __launch_bounds__(256, 4) void ssim_main(const float* __restrict__ img1,
                                                    const float* __restrict__ img2,
                                                    const float* __restrict__ window,
                                                    float* __restrict__ ws)
{
    const int lane = threadIdx.x & 63;
    const int wid  = blockIdx.x * 4 + (threadIdx.x >> 6);   // 4 independent waves/block
    const int ch = wid % CHD;                // row chunk 0..15
    const int bs = wid / CHD;
    const int s  = bs % NSTRIP;              // col strip 0..8
    const int b  = bs / NSTRIP;              // batch 0..31

    const int R0 = ch * RH;
    const int CS = s * SOUT - 6;             // even -> float2-aligned
    const int c0 = CS + 2 * lane;
    const int c1 = c0 + 1;

    // output validity (each global col produced by exactly one strip)
    const int olo = s * SOUT, ohi = min(olo + SOUT, WW);
    const float ov0 = (c0 >= olo && c0 < ohi) ? 1.f : 0.f;
    const float ov1 = (c1 >= olo && c1 < ohi) ? 1.f : 0.f;
    // load validity (zero-pad outside image)
    const bool lv0 = ((unsigned)c0 < (unsigned)WW);
    const bool lv1 = ((unsigned)c1 < (unsigned)WW);
    const int  ccl = min(max(c0, 0), WW - 2);                // clamped even col

    const size_t ib = (size_t)b * (size_t)(HH * WW) + (size_t)ccl;
    const float* B1 = img1 + ib;
    const float* B2 = img2 + ib;
    const float w = window[0];

    // bpermute byte-addresses for constant lane shifts (hw wraps mod 64;
    // wrapped values only reach masked-out halo lanes)
    const int am1 = (lane - 1) << 2, ap1 = (lane + 1) << 2;
    const int am2 = (lane - 2) << 2, ap2 = (lane + 2) << 2;
    const int am3 = (lane - 3) << 2, ap3 = (lane + 3) << 2;

    // 11-deep register ring (static indices only)
    float rx0[11], rx1[11], ry0[11], ry1[11];
#pragma unroll
    for (int u = 0; u < 11; ++u) { rx0[u]=0.f; rx1[u]=0.f; ry0[u]=0.f; ry1[u]=0.f; }

    float s1a=0.f,s2a=0.f,spa=0.f,sqa=0.f;   // col c0: sum x, sum y, sum (x+y)^2, sum (x-y)^2
    float s1b=0.f,s2b=0.f,spb=0.f,sqb=0.f;   // col c1

    // ---- prologue: rows R0-5 .. R0+4 -> slots 0..9 (slot 10 stays zero) ----
#pragma unroll
    for (int u = 0; u < 10; ++u) {
        const int j  = R0 - 5 + u;
        const int jc = max(j, 0);
        const float2 X = *(const float2*)(B1 + (size_t)jc * WW);
        const float2 Y = *(const float2*)(B2 + (size_t)jc * WW);
        const bool rv = (j >= 0);
        const float x0 = (rv && lv0) ? X.x : 0.f, x1 = (rv && lv1) ? X.y : 0.f;
        const float y0 = (rv && lv0) ? Y.x : 0.f, y1 = (rv && lv1) ? Y.y : 0.f;
        rx0[u]=x0; rx1[u]=x1; ry0[u]=y0; ry1[u]=y1;
        { const float aa=x0+y0, dd=x0-y0; s1a+=x0; s2a+=y0; spa+=aa*aa; sqa+=dd*dd; }
        { const float aa=x1+y1, dd=x1-y1; s1b+=x1; s2b+=y1; spb+=aa*aa; sqb+=dd*dd; }
    }

    float ssum = 0.f;
    int m = 0;
    // ---- main: 66 rows = 6 groups x 11 (ring slot static); outputs masked to m<RH ----
#pragma unroll 1
    for (int g = 0; g < 6; ++g) {
#pragma unroll
        for (int u = 0; u < 11; ++u) {
            const int slot = (10 + u) % 11;              // compile-time
            const int j  = R0 + 5 + m;
            const int jc = min(j, HH - 1);
            const float2 X = *(const float2*)(B1 + (size_t)jc * WW);
            const float2 Y = *(const float2*)(B2 + (size_t)jc * WW);
            const bool rv = (j < HH);
            const float x0 = (rv && lv0) ? X.x : 0.f, x1 = (rv && lv1) ? X.y : 0.f;
            const float y0 = (rv && lv0) ? Y.x : 0.f, y1 = (rv && lv1) ? Y.y : 0.f;

            // vertical running sums: add row j, drop row j-11 (ring slot)
            {   const float xo = rx0[slot], yo = ry0[slot];
                const float aa = x0+y0, dd = x0-y0, ao = xo+yo, dn = xo-yo;
                s1a += x0 - xo; s2a += y0 - yo;
                spa += (aa - ao) * (aa + ao);
                sqa += (dd - dn) * (dd + dn);
                rx0[slot] = x0; ry0[slot] = y0; }
            {   const float xo = rx1[slot], yo = ry1[slot];
                const float aa = x1+y1, dd = x1-y1, ao = xo+yo, dn = xo-yo;
                s1b += x1 - xo; s2b += y1 - yo;
                spb += (aa - ao) * (aa + ao);
                sqb += (dd - dn) * (dd + dn);
                rx1[slot] = x1; ry1[slot] = y1; }

            // horizontal 11-tap across lanes: S(c0)=T+v1(l-3), S(c1)=T+v0(l+3),
            // T = 5-tap of pair sums P
            const float P1 = s1a+s1b, P2 = s2a+s2b, Pp = spa+spb, Pq = sqa+sqb;
            const float T1 = P1 + shf(am1,P1) + shf(ap1,P1) + shf(am2,P1) + shf(ap2,P1);
            const float T2 = P2 + shf(am1,P2) + shf(ap1,P2) + shf(am2,P2) + shf(ap2,P2);
            const float Tp = Pp + shf(am1,Pp) + shf(ap1,Pp) + shf(am2,Pp) + shf(ap2,Pp);
            const float Tq = Pq + shf(am1,Pq) + shf(ap1,Pq) + shf(am2,Pq) + shf(ap2,Pq);
            const float S1_0 = T1 + shf(am3, s1b), S1_1 = T1 + shf(ap3, s1a);
            const float S2_0 = T2 + shf(am3, s2b), S2_1 = T2 + shf(ap3, s2a);
            const float Sp_0 = Tp + shf(am3, spb), Sp_1 = Tp + shf(ap3, spa);
            const float Sq_0 = Tq + shf(am3, sqb), Sq_1 = Tq + shf(ap3, sqa);

            const float rowv = (m < RH) ? 1.f : 0.f;
            const float fm0 = rowv * ov0, fm1 = rowv * ov1;
            {   const float mu1 = S1_0*w, mu2 = S2_0*w, Pb = Sp_0*w, Qb = Sq_0*w;
                const float m11 = mu1*mu1, m22 = mu2*mu2, m12 = mu1*mu2;
                const float sigs = 0.5f  * (Pb + Qb) - m11 - m22;
                const float s12  = 0.25f * (Pb - Qb) - m12;
                const float num  = (2.f*m12 + SSIM_C1) * (2.f*s12 + SSIM_C2);
                const float den  = (m11 + m22 + SSIM_C1) * (sigs + SSIM_C2);
                ssum += fm0 * (num * __builtin_amdgcn_rcpf(den)); }
            {   const float mu1 = S1_1*w, mu2 = S2_1*w, Pb = Sp_1*w, Qb = Sq_1*w;
                const float m11 = mu1*mu1, m22 = mu2*mu2, m12 = mu1*mu2;
                const float sigs = 0.5f  * (Pb + Qb) - m11 - m22;
                const float s12  = 0.25f * (Pb - Qb) - m12;
                const float num  = (2.f*m12 + SSIM_C1) * (2.f*s12 + SSIM_C2);
                const float den  = (m11 + m22 + SSIM_C1) * (sigs + SSIM_C2);
                ssum += fm1 * (num * __builtin_amdgcn_rcpf(den)); }
            ++m;
        }
    }

    // ---- wave reduction -> one atomicAdd per wave ----
    float v = ssum;
#pragma unroll
    for (int off = 32; off; off >>= 1) v += __shfl_down(v, off, 64);
    if (lane == 0) atomicAdd(ws, v);
}

__global__ void ssim_fin(const float* __restrict__ ws, float* __restrict__ out, int ntot) {
    out[0] = 1.f - ws[0] / (float)ntot;
}

extern "C" void kernel_launch(void* const* d_in, const int* in_sizes, int n_in,
                              void* d_out, int out_size, void* d_ws, size_t ws_size,
                              hipStream_t stream) {
    const float* img1 = (const float*)d_in[0];
    const float* img2 = (const float*)d_in[1];
    const float* win  = (const float*)d_in[2];
    float* out = (float*)d_out;
    float* ws  = (float*)d_ws;
    const int ntot = in_sizes[0];                        // 32*1024*1024
    const int batches = ntot / (HH * WW);                // 32

    ssim_ws_init<<<dim3(1), dim3(1), 0, stream>>>(ws);
    const int nwaves  = batches * NSTRIP * CHD;          // 4608
    const int nblocks = nwaves / 4;                      // 1152
    ssim_main<<<dim3(nblocks), dim3(256), 0, stream>>>(img1, img2, win, ws);
    ssim_fin<<<dim3(1), dim3(1), 0, stream>>>(ws, out, ntot);
}

// Round 5
// 148.464 us; speedup vs baseline: 2.9531x; 2.9531x over previous
//
#include <hip/hip_runtime.h>

#define HH 1024
#define WW 1024
#define TH 16          // output rows per tile
#define TW 116         // output cols per tile (even -> float2-aligned halo)
#define WL 128         // colsum slots = halo cols C0-6 .. C0+121
#define WLP 144        // padded row stride (prefetch overrun safety)
#define NSLOT 1024     // partial-sum slots (atomic contention spread)
#define SSIM_C1 1e-4f
#define SSIM_C2 9e-4f

__global__ void ssim_ws_init(float* ws) { ws[threadIdx.x] = 0.f; }

__global__ __launch_bounds__(256, 4) void ssim_main(const float* __restrict__ img1,
                                                    const float* __restrict__ img2,
                                                    const float* __restrict__ window,
                                                    float* __restrict__ ws)
{
    __shared__ float4 cs4[TH][WLP];  // 36 KB: colsums {s1,s2,(x+y)^2,(x-y)^2}

    const int tx = blockIdx.x;       // col tile: 0..8
    const int ty = blockIdx.y;       // row tile: 0..63
    const int b  = blockIdx.z;       // batch
    const int C0 = tx * TW;
    const int R0 = ty * TH;
    const int t  = threadIdx.x;
    const size_t ibase = (size_t)b * (size_t)(HH * WW);
    const float w = window[0];

    // ---- Phase 1: vertical 11-row sums. 64 col-pair threads x 4 row-chunks.
    // Running prefix + 3 snapshots (out[i]=P[i+10]-P[i-1]).
    {
        const int cg = t & 63;           // column pair: slots 2cg, 2cg+1
        const int q  = t >> 6;           // row chunk 0..3 (one wave each)
        const int gc = C0 - 6 + 2 * cg;  // even -> 8B-aligned float2
        const bool cok = (unsigned)gc < (unsigned)WW;
        const float2* p1 = (const float2*)(img1 + ibase + gc);
        const float2* p2 = (const float2*)(img2 + ibase + gc);
        const int jbase = R0 - 5 + 4 * q;

        float2 X[14], Y[14];
#pragma unroll
        for (int k = 0; k < 14; ++k) {
            const int j = jbase + k;
            float2 x = make_float2(0.f, 0.f), y = make_float2(0.f, 0.f);
            if (cok && (unsigned)j < (unsigned)HH) {
                const size_t off = (size_t)j * (WW / 2);
                x = p1[off];
                y = p2[off];
            }
            X[k] = x; Y[k] = y;
        }

        float s1a=0.f,s2a=0.f,spa=0.f,sqa=0.f;
        float s1b=0.f,s2b=0.f,spb=0.f,sqb=0.f;
        float sn[3][8];
#pragma unroll
        for (int k = 0; k < 14; ++k) {
            const float2 x = X[k], y = Y[k];
            { const float aa = x.x + y.x, dd = x.x - y.x;
              s1a += x.x; s2a += y.x; spa += aa * aa; sqa += dd * dd; }
            { const float aa = x.y + y.y, dd = x.y - y.y;
              s1b += x.y; s2b += y.y; spb += aa * aa; sqb += dd * dd; }
            if (k < 3) {
                sn[k][0]=s1a; sn[k][1]=s2a; sn[k][2]=spa; sn[k][3]=sqa;
                sn[k][4]=s1b; sn[k][5]=s2b; sn[k][6]=spb; sn[k][7]=sqb;
            }
            if (k >= 10) {
                const int i = k - 10;
                const int r = 4 * q + i;
                const int sx = r & 7;
                float4 va, vb;
                if (i == 0) {
                    va.x=s1a; va.y=s2a; va.z=spa; va.w=sqa;
                    vb.x=s1b; vb.y=s2b; vb.z=spb; vb.w=sqb;
                } else {
                    va.x=s1a-sn[i-1][0]; va.y=s2a-sn[i-1][1];
                    va.z=spa-sn[i-1][2]; va.w=sqa-sn[i-1][3];
                    vb.x=s1b-sn[i-1][4]; vb.y=s2b-sn[i-1][5];
                    vb.z=spb-sn[i-1][6]; vb.w=sqb-sn[i-1][7];
                }
                cs4[r][(2 * cg)     ^ sx] = va;
                cs4[r][(2 * cg + 1) ^ sx] = vb;
            }
        }
    }
    __syncthreads();

    // ---- Phase 2: prefetch 19 colsums, then 11-tap sliding window + SSIM ----
    float ssum = 0.f;
    {
        const int r   = t & 15;
        const int seg = t >> 4;              // 16 segments x 8 cols
        const int c0  = seg * 8;
        const int TWa = min(TW, WW - C0);    // ragged last col-tile (96)
        const int S   = min(8, TWa - c0);
        if (S > 0) {
            const int sx = r & 7;
            float4 v[19];
#pragma unroll
            for (int k = 0; k < 19; ++k)
                v[k] = cs4[r][(c0 + k) ^ sx];   // max idx 138 < WLP

            float4 win4; win4.x = win4.y = win4.z = win4.w = 0.f;
#pragma unroll
            for (int k = 1; k <= 10; ++k) {
                win4.x += v[k].x; win4.y += v[k].y; win4.z += v[k].z; win4.w += v[k].w;
            }
#pragma unroll
            for (int p = 0; p < 8; ++p) {
                if (p >= S) break;
                win4.x += v[p+11].x; win4.y += v[p+11].y;
                win4.z += v[p+11].z; win4.w += v[p+11].w;

                const float mu1  = win4.x * w;
                const float mu2  = win4.y * w;
                const float P    = win4.z * w;   // box((x+y)^2)
                const float Q    = win4.w * w;   // box((x-y)^2)
                const float mu11 = mu1 * mu1;
                const float mu22 = mu2 * mu2;
                const float mu12 = mu1 * mu2;
                const float sigs = 0.5f  * (P + Q) - mu11 - mu22;
                const float s12  = 0.25f * (P - Q) - mu12;
                const float num  = (2.f * mu12 + SSIM_C1) * (2.f * s12 + SSIM_C2);
                const float den  = (mu11 + mu22 + SSIM_C1) * (sigs + SSIM_C2);
                ssum += num * __builtin_amdgcn_rcpf(den);

                win4.x -= v[p+1].x; win4.y -= v[p+1].y;
                win4.z -= v[p+1].z; win4.w -= v[p+1].w;
            }
        }
    }

    // ---- Per-wave reduction -> atomicAdd into spread slots (contention fix) ----
    float v = ssum;
#pragma unroll
    for (int off = 32; off > 0; off >>= 1) v += __shfl_down(v, off, 64);
    if ((t & 63) == 0) {
        const int bid  = blockIdx.x + 9 * (blockIdx.y + 64 * blockIdx.z);
        const int slot = (bid * 4 + (t >> 6)) & (NSLOT - 1);
        atomicAdd(ws + slot, v);
    }
}

__global__ void ssim_fin(const float* __restrict__ ws, float* __restrict__ out, int ntot) {
    const int lane = threadIdx.x;        // 64 threads
    float v = 0.f;
#pragma unroll
    for (int k = 0; k < NSLOT / 64; ++k) v += ws[lane + 64 * k];
#pragma unroll
    for (int off = 32; off > 0; off >>= 1) v += __shfl_down(v, off, 64);
    if (lane == 0) out[0] = 1.f - v / (float)ntot;
}

extern "C" void kernel_launch(void* const* d_in, const int* in_sizes, int n_in,
                              void* d_out, int out_size, void* d_ws, size_t ws_size,
                              hipStream_t stream) {
    const float* img1 = (const float*)d_in[0];
    const float* img2 = (const float*)d_in[1];
    const float* win  = (const float*)d_in[2];
    float* out = (float*)d_out;
    float* ws  = (float*)d_ws;
    const int ntot = in_sizes[0];                       // 32*1024*1024
    const int batches = ntot / (HH * WW);               // 32

    ssim_ws_init<<<dim3(1), dim3(NSLOT), 0, stream>>>(ws);
    dim3 grid((WW + TW - 1) / TW, HH / TH, batches);    // 9 x 64 x 32
    ssim_main<<<grid, dim3(256), 0, stream>>>(img1, img2, win, ws);
    ssim_fin<<<dim3(1), dim3(64), 0, stream>>>(ws, out, ntot);
}

// Round 6
// 100.066 us; speedup vs baseline: 4.3814x; 1.4837x over previous
//
#include <hip/hip_runtime.h>

#define HH 1024
#define WW 1024
#define TH 16          // output rows per tile
#define TW 116         // output cols per tile (even -> float2-aligned halo)
#define WLP 144        // padded colsum row stride
#define NSLOT 1024     // partial-sum slots (atomic contention spread)
#define SSIM_C1 1e-4f
#define SSIM_C2 9e-4f

__global__ void ssim_ws_init(float* ws) { ws[threadIdx.x] = 0.f; }

__global__ __launch_bounds__(256, 4) void ssim_main(const float* __restrict__ img1,
                                                    const float* __restrict__ img2,
                                                    const float* __restrict__ window,
                                                    float* __restrict__ ws)
{
    __shared__ float4 cs4[TH][WLP];  // 36 KB: colsums {s1,s2,(x+y)^2,(x-y)^2}

    const int tx = blockIdx.x;       // col tile: 0..8
    const int ty = blockIdx.y;       // row tile: 0..63
    const int b  = blockIdx.z;       // batch
    const int C0 = tx * TW;
    const int R0 = ty * TH;
    const int t  = threadIdx.x;
    const size_t ibase = (size_t)b * (size_t)(HH * WW);
    const float w = window[0];

    // ---- Phase 1: vertical 11-row sums. 64 col-pair threads x 4 row-chunks.
    // Load ALL 14 float2-rows first (pinned by sched_barrier), then
    // running prefix + 3 snapshots (out[i] = P[i+10] - P[i-1]).
    {
        const int cg = t & 63;           // column pair: slots 2cg, 2cg+1
        const int q  = t >> 6;           // row chunk 0..3 (one wave each)
        const int gc = C0 - 6 + 2 * cg;  // even -> 8B-aligned float2
        const int jbase = R0 - 5 + 4 * q;

        float2 X[14], Y[14];
        const bool interior = (ty >= 1) && (ty <= 62) && (tx >= 1) && (tx <= 7);
        if (interior) {
            const float2* p1 = (const float2*)(img1 + ibase + gc);
            const float2* p2 = (const float2*)(img2 + ibase + gc);
#pragma unroll
            for (int k = 0; k < 14; ++k) {
                const size_t off = (size_t)(jbase + k) * (WW / 2);
                X[k] = p1[off];
                Y[k] = p2[off];
            }
        } else {
            const bool cok = (unsigned)gc < (unsigned)WW;
            const int gcc = min(max(gc, 0), WW - 2);
            const float2* p1 = (const float2*)(img1 + ibase + gcc);
            const float2* p2 = (const float2*)(img2 + ibase + gcc);
#pragma unroll
            for (int k = 0; k < 14; ++k) {
                const int j  = jbase + k;
                const int jc = min(max(j, 0), HH - 1);
                const size_t off = (size_t)jc * (WW / 2);
                float2 x = p1[off], y = p2[off];
                const bool ok = cok && ((unsigned)j < (unsigned)HH);
                if (!ok) { x = make_float2(0.f, 0.f); y = make_float2(0.f, 0.f); }
                X[k] = x; Y[k] = y;
            }
        }
        __builtin_amdgcn_sched_barrier(0);   // keep all 28 loads in flight

        float s1a=0.f,s2a=0.f,spa=0.f,sqa=0.f;
        float s1b=0.f,s2b=0.f,spb=0.f,sqb=0.f;
        float sn[3][8];
#pragma unroll
        for (int k = 0; k < 14; ++k) {
            const float2 x = X[k], y = Y[k];
            { const float aa = x.x + y.x, dd = x.x - y.x;
              s1a += x.x; s2a += y.x; spa += aa * aa; sqa += dd * dd; }
            { const float aa = x.y + y.y, dd = x.y - y.y;
              s1b += x.y; s2b += y.y; spb += aa * aa; sqb += dd * dd; }
            if (k < 3) {
                sn[k][0]=s1a; sn[k][1]=s2a; sn[k][2]=spa; sn[k][3]=sqa;
                sn[k][4]=s1b; sn[k][5]=s2b; sn[k][6]=spb; sn[k][7]=sqb;
            }
            if (k >= 10) {
                const int i = k - 10;
                const int r = 4 * q + i;
                const int sx = r & 7;
                float4 va, vb;
                if (i == 0) {
                    va.x=s1a; va.y=s2a; va.z=spa; va.w=sqa;
                    vb.x=s1b; vb.y=s2b; vb.z=spb; vb.w=sqb;
                } else {
                    va.x=s1a-sn[i-1][0]; va.y=s2a-sn[i-1][1];
                    va.z=spa-sn[i-1][2]; va.w=sqa-sn[i-1][3];
                    vb.x=s1b-sn[i-1][4]; vb.y=s2b-sn[i-1][5];
                    vb.z=spb-sn[i-1][6]; vb.w=sqb-sn[i-1][7];
                }
                cs4[r][(2 * cg)     ^ sx] = va;
                cs4[r][(2 * cg + 1) ^ sx] = vb;
            }
        }
    }
    __syncthreads();

    // ---- Phase 2: prefetch 19 colsums (pinned), then sliding window + SSIM ----
    float ssum = 0.f;
    {
        const int r   = t & 15;
        const int seg = t >> 4;              // 16 segments x 8 cols
        const int c0  = seg * 8;
        const int TWa = min(TW, WW - C0);    // ragged last col-tile (96)
        const int S   = min(8, TWa - c0);
        if (S > 0) {
            const int sx = r & 7;
            float4 v[19];
#pragma unroll
            for (int k = 0; k < 19; ++k)
                v[k] = cs4[r][(c0 + k) ^ sx];   // max idx 133 < WLP
            __builtin_amdgcn_sched_barrier(0);  // keep 19 ds_reads batched

            float4 win4; win4.x = win4.y = win4.z = win4.w = 0.f;
#pragma unroll
            for (int k = 1; k <= 10; ++k) {
                win4.x += v[k].x; win4.y += v[k].y; win4.z += v[k].z; win4.w += v[k].w;
            }
#pragma unroll
            for (int p = 0; p < 8; ++p) {
                if (p >= S) break;
                win4.x += v[p+11].x; win4.y += v[p+11].y;
                win4.z += v[p+11].z; win4.w += v[p+11].w;

                const float mu1  = win4.x * w;
                const float mu2  = win4.y * w;
                const float P    = win4.z * w;   // box((x+y)^2)
                const float Q    = win4.w * w;   // box((x-y)^2)
                const float mu11 = mu1 * mu1;
                const float mu22 = mu2 * mu2;
                const float mu12 = mu1 * mu2;
                const float sigs = 0.5f  * (P + Q) - mu11 - mu22;
                const float s12  = 0.25f * (P - Q) - mu12;
                const float num  = (2.f * mu12 + SSIM_C1) * (2.f * s12 + SSIM_C2);
                const float den  = (mu11 + mu22 + SSIM_C1) * (sigs + SSIM_C2);
                ssum += num * __builtin_amdgcn_rcpf(den);

                win4.x -= v[p+1].x; win4.y -= v[p+1].y;
                win4.z -= v[p+1].z; win4.w -= v[p+1].w;
            }
        }
    }

    // ---- Per-wave reduction -> atomicAdd into spread slots ----
    float v = ssum;
#pragma unroll
    for (int off = 32; off > 0; off >>= 1) v += __shfl_down(v, off, 64);
    if ((t & 63) == 0) {
        const int bid  = blockIdx.x + 9 * (blockIdx.y + 64 * blockIdx.z);
        const int slot = (bid * 4 + (t >> 6)) & (NSLOT - 1);
        atomicAdd(ws + slot, v);
    }
}

__global__ void ssim_fin(const float* __restrict__ ws, float* __restrict__ out, int ntot) {
    const int lane = threadIdx.x;        // 64 threads
    float v = 0.f;
#pragma unroll
    for (int k = 0; k < NSLOT / 64; ++k) v += ws[lane + 64 * k];
#pragma unroll
    for (int off = 32; off > 0; off >>= 1) v += __shfl_down(v, off, 64);
    if (lane == 0) out[0] = 1.f - v / (float)ntot;
}

extern "C" void kernel_launch(void* const* d_in, const int* in_sizes, int n_in,
                              void* d_out, int out_size, void* d_ws, size_t ws_size,
                              hipStream_t stream) {
    const float* img1 = (const float*)d_in[0];
    const float* img2 = (const float*)d_in[1];
    const float* win  = (const float*)d_in[2];
    float* out = (float*)d_out;
    float* ws  = (float*)d_ws;
    const int ntot = in_sizes[0];                       // 32*1024*1024
    const int batches = ntot / (HH * WW);               // 32

    ssim_ws_init<<<dim3(1), dim3(NSLOT), 0, stream>>>(ws);
    dim3 grid((WW + TW - 1) / TW, HH / TH, batches);    // 9 x 64 x 32
    ssim_main<<<grid, dim3(256), 0, stream>>>(img1, img2, win, ws);
    ssim_fin<<<dim3(1), dim3(64), 0, stream>>>(ws, out, ntot);
}

// Round 8
// 96.783 us; speedup vs baseline: 4.5300x; 1.0339x over previous
//
#include <hip/hip_runtime.h>

#define HH 1024
#define WW 1024
#define TH 16          // output rows per tile
#define TW 116         // output cols per tile (even -> float2-aligned halo)
#define WLP 144        // padded colsum row stride
#define NSLOT 1024     // partial-sum slots (atomic contention spread)
#define SSIM_C1 1e-4f
#define SSIM_C2 9e-4f

__global__ void ssim_ws_init(float* ws) { ws[threadIdx.x] = 0.f; }

__global__ __launch_bounds__(256, 4) void ssim_main(const float* __restrict__ img1,
                                                    const float* __restrict__ img2,
                                                    const float* __restrict__ window,
                                                    float* __restrict__ ws)
{
    __shared__ float4 cs4[TH][WLP];  // 36 KB: colsums {S1,S2,sum(x+y)^2,sum(x-y)^2}

    const int tx = blockIdx.x;       // col tile: 0..8
    const int ty = blockIdx.y;       // row tile: 0..63
    const int b  = blockIdx.z;       // batch
    const int C0 = tx * TW;
    const int R0 = ty * TH;
    const int t  = threadIdx.x;
    const size_t ibase = (size_t)b * (size_t)(HH * WW);
    const float w = window[0];

    // ---- Phase 1: vertical 11-row sums. 64 col-pairs x 2 chunks of 8 rows.
    // Thread loads 18 rows, accumulates first 11, then ring-slides (add row
    // 10+i, drop row i-1) emitting 8 colsum rows. Static indices via unroll.
    {
        const int cg = t & 63;           // column pair: slots 2cg, 2cg+1
        const int q  = t >> 6;           // chunk 0..3; only q<2 active
        if (q < 2) {
            const int gc = C0 - 6 + 2 * cg;  // even -> 8B-aligned float2
            const int jbase = R0 - 5 + 8 * q;

            float2 X[18], Y[18];
            const bool interior = (ty >= 1) && (ty <= 62) && (tx >= 1) && (tx <= 7);
            if (interior) {
                const float2* p1 = (const float2*)(img1 + ibase + gc);
                const float2* p2 = (const float2*)(img2 + ibase + gc);
#pragma unroll
                for (int k = 0; k < 18; ++k) {
                    const size_t off = (size_t)(jbase + k) * (WW / 2);
                    X[k] = p1[off];
                    Y[k] = p2[off];
                }
            } else {
                const bool cok = (unsigned)gc < (unsigned)WW;
                const int gcc = min(max(gc, 0), WW - 2);
                const float2* p1 = (const float2*)(img1 + ibase + gcc);
                const float2* p2 = (const float2*)(img2 + ibase + gcc);
#pragma unroll
                for (int k = 0; k < 18; ++k) {
                    const int j  = jbase + k;
                    const int jc = min(max(j, 0), HH - 1);
                    const size_t off = (size_t)jc * (WW / 2);
                    float2 x = p1[off], y = p2[off];
                    const bool ok = cok && ((unsigned)j < (unsigned)HH);
                    if (!ok) { x = make_float2(0.f, 0.f); y = make_float2(0.f, 0.f); }
                    X[k] = x; Y[k] = y;
                }
            }
            __builtin_amdgcn_sched_barrier(0);   // keep loads batched in flight

            float s1a=0.f,s2a=0.f,spa=0.f,sqa=0.f;
            float s1b=0.f,s2b=0.f,spb=0.f,sqb=0.f;
#pragma unroll
            for (int k = 0; k < 11; ++k) {
                const float2 x = X[k], y = Y[k];
                { const float aa = x.x + y.x, dd = x.x - y.x;
                  s1a += x.x; s2a += y.x; spa += aa * aa; sqa += dd * dd; }
                { const float aa = x.y + y.y, dd = x.y - y.y;
                  s1b += x.y; s2b += y.y; spb += aa * aa; sqb += dd * dd; }
            }
#pragma unroll
            for (int i = 0; i < 8; ++i) {
                if (i > 0) {
                    const float2 xn = X[10 + i], yn = Y[10 + i];   // static idx
                    const float2 xo = X[i - 1],  yo = Y[i - 1];
                    {   const float an = xn.x + yn.x, dn = xn.x - yn.x;
                        const float ao = xo.x + yo.x, dof = xo.x - yo.x;
                        s1a += xn.x - xo.x; s2a += yn.x - yo.x;
                        spa += (an - ao) * (an + ao);
                        sqa += (dn - dof) * (dn + dof); }
                    {   const float an = xn.y + yn.y, dn = xn.y - yn.y;
                        const float ao = xo.y + yo.y, dof = xo.y - yo.y;
                        s1b += xn.y - xo.y; s2b += yn.y - yo.y;
                        spb += (an - ao) * (an + ao);
                        sqb += (dn - dof) * (dn + dof); }
                }
                const int r  = 8 * q + i;
                const int sx = r & 7;
                float4 va; va.x=s1a; va.y=s2a; va.z=spa; va.w=sqa;
                float4 vb; vb.x=s1b; vb.y=s2b; vb.z=spb; vb.w=sqb;
                cs4[r][(2 * cg)     ^ sx] = va;
                cs4[r][(2 * cg + 1) ^ sx] = vb;
            }
        }
    }
    __syncthreads();

    // ---- Phase 2: prefetch 19 colsums (pinned), sliding window + SSIM ----
    // Raw-sum space: mu-products use raw S1,S2; second moments need the
    // extra u=1/w factor: sigs = 0.5u(P+Q) - m11 - m22, s12 = 0.25u(P-Q) - m12,
    // with C1' = C1*u^2, C2' = C2*u^2 (everything then scales as w^4/w^4).
    float ssum = 0.f;
    {
        const float u   = __builtin_amdgcn_rcpf(w);   // = 121
        const float C1p = SSIM_C1 * u * u;
        const float C2p = SSIM_C2 * u * u;
        const int r   = t & 15;
        const int seg = t >> 4;              // 16 segments x 8 cols
        const int c0  = seg * 8;
        const int TWa = min(TW, WW - C0);    // ragged last col-tile (96)
        const int S   = min(8, TWa - c0);
        if (S > 0) {
            const int sx = r & 7;
            float4 v[19];
#pragma unroll
            for (int k = 0; k < 19; ++k)
                v[k] = cs4[r][(c0 + k) ^ sx];   // max idx < WLP
            __builtin_amdgcn_sched_barrier(0);  // keep 19 ds_reads batched

            float4 win4; win4.x = win4.y = win4.z = win4.w = 0.f;
#pragma unroll
            for (int k = 1; k <= 10; ++k) {
                win4.x += v[k].x; win4.y += v[k].y; win4.z += v[k].z; win4.w += v[k].w;
            }
#pragma unroll
            for (int p = 0; p < 8; ++p) {
                if (p >= S) break;
                win4.x += v[p+11].x; win4.y += v[p+11].y;
                win4.z += v[p+11].z; win4.w += v[p+11].w;

                const float S1 = win4.x, S2 = win4.y;
                const float P  = win4.z, Q  = win4.w;
                const float m11 = S1 * S1;
                const float m22 = S2 * S2;
                const float m12 = S1 * S2;
                const float A    = 0.5f  * (P + Q) * u;
                const float Bv   = 0.25f * (P - Q) * u;
                const float sigs = A  - m11 - m22;
                const float s12  = Bv - m12;
                const float num  = (2.f * m12 + C1p) * (2.f * s12 + C2p);
                const float den  = (m11 + m22 + C1p) * (sigs + C2p);
                ssum += num * __builtin_amdgcn_rcpf(den);

                win4.x -= v[p+1].x; win4.y -= v[p+1].y;
                win4.z -= v[p+1].z; win4.w -= v[p+1].w;
            }
        }
    }

    // ---- Per-wave reduction -> atomicAdd into spread slots ----
    float v = ssum;
#pragma unroll
    for (int off = 32; off > 0; off >>= 1) v += __shfl_down(v, off, 64);
    if ((t & 63) == 0) {
        const int bid  = blockIdx.x + 9 * (blockIdx.y + 64 * blockIdx.z);
        const int slot = (bid * 4 + (t >> 6)) & (NSLOT - 1);
        atomicAdd(ws + slot, v);
    }
}

__global__ void ssim_fin(const float* __restrict__ ws, float* __restrict__ out, int ntot) {
    const int lane = threadIdx.x;        // 64 threads
    float v = 0.f;
#pragma unroll
    for (int k = 0; k < NSLOT / 64; ++k) v += ws[lane + 64 * k];
#pragma unroll
    for (int off = 32; off > 0; off >>= 1) v += __shfl_down(v, off, 64);
    if (lane == 0) out[0] = 1.f - v / (float)ntot;
}

extern "C" void kernel_launch(void* const* d_in, const int* in_sizes, int n_in,
                              void* d_out, int out_size, void* d_ws, size_t ws_size,
                              hipStream_t stream) {
    const float* img1 = (const float*)d_in[0];
    const float* img2 = (const float*)d_in[1];
    const float* win  = (const float*)d_in[2];
    float* out = (float*)d_out;
    float* ws  = (float*)d_ws;
    const int ntot = in_sizes[0];                       // 32*1024*1024
    const int batches = ntot / (HH * WW);               // 32

    ssim_ws_init<<<dim3(1), dim3(NSLOT), 0, stream>>>(ws);
    dim3 grid((WW + TW - 1) / TW, HH / TH, batches);    // 9 x 64 x 32
    ssim_main<<<grid, dim3(256), 0, stream>>>(img1, img2, win, ws);
    ssim_fin<<<dim3(1), dim3(64), 0, stream>>>(ws, out, ntot);
}